// Round 2
// baseline (4359.967 us; speedup 1.0000x reference)
//
#include <hip/hip_runtime.h>
#include <cstdint>
#include <cstddef>

// Problem constants
#define B_   64
#define S_   512
#define ISZ  256
#define HSZ  512
#define NG   2048    // 4*H

typedef unsigned short u16;
typedef unsigned int   u32;
typedef unsigned long long u64;
typedef __attribute__((ext_vector_type(8))) short short8;
typedef __attribute__((ext_vector_type(4))) float floatx4;

// Workspace layout (bytes), total ~57.3 MB
static const size_t OFF_WPACK = 0;                        // 2*2048*768*2 = 6,291,456
static const size_t OFF_XB    = 6291456;                  // 512*64*256*2 = 16,777,216
static const size_t OFF_HB    = OFF_XB + 16777216;        // tagged h tiles: 2 parity * 2 dir * 4 bg * 32 c * 256 u32 * 4B = 524,288
static const size_t OFF_FLAGS = OFF_HB + 524288;          // spread flags: 2 parity * 8 chain * 32 c * 256B = 131,072
static const size_t OFF_STAGE = OFF_FLAGS + 131072;       // 512*64*512*2B = 33,554,432 (bwd h, bf16)

__device__ __forceinline__ u16 f2bf(float f) {
    uint32_t u = __float_as_uint(f);
    return (u16)((u + 0x7fffu + ((u >> 16) & 1u)) >> 16);  // RNE
}
__device__ __forceinline__ float sigmoidf_(float x) {
    return 1.0f / (1.0f + __expf(-x));
}
__device__ __forceinline__ float tanhf_(float x) {
    return 1.0f - 2.0f / (__expf(2.0f * x) + 1.0f);
}

// ---------------------------------------------------------------------------
// Pack W_f / W_b (768 x 2048 f32, row-major) into bf16 MFMA-B-fragment order,
// gate-interleaved per 16-hidden-unit chunk:
//   flat = ((dir*128 + nb)*24 + kb)*512 + lane*8 + j ;  nb = 4c+gate
// ---------------------------------------------------------------------------
__global__ __launch_bounds__(256) void pack_w(const float* __restrict__ Wf,
                                              const float* __restrict__ Wb,
                                              u16* __restrict__ wpack) {
    int tid = blockIdx.x * 256 + threadIdx.x;   // over 768*2048
    int dir = blockIdx.y;
    int p = tid & 2047;
    int k = tid >> 11;
    int gate = (p >> 4) & 3;
    int hid  = (p >> 6) * 16 + (p & 15);
    int col  = gate * HSZ + hid;
    const float* W = dir ? Wb : Wf;
    float v = W[(size_t)k * NG + col];
    int nb   = p >> 4;
    int lane = ((k & 31) >> 3) * 16 + (p & 15);
    size_t idx = (((size_t)(dir * 128 + nb) * 24 + (k >> 5)) * 512) + lane * 8 + (k & 7);
    wpack[idx] = f2bf(v);
}

// inputs (B,S,I) f32 -> Xb [t][b][i] bf16
__global__ __launch_bounds__(256) void pack_x(const float* __restrict__ x,
                                              u16* __restrict__ xb) {
    int tid = blockIdx.x * 256 + threadIdx.x;   // over S*B*I = 8,388,608
    int i = tid & 255;
    int b = (tid >> 8) & 63;
    int t = tid >> 14;
    xb[tid] = f2bf(x[((size_t)b * S_ + t) * ISZ + i]);
}

// ---------------------------------------------------------------------------
// Persistent BiLSTM. grid = 256 blocks x 64 threads (one wave per block).
//   chain = blockIdx&7 (dir = chain>>2, bg = chain&3), c = blockIdx>>3.
//   (blockIdx&7 == XCD id under round-robin dispatch -> each 32-block chain
//    group is XCD-local.)
//
// Handshake, v3 (hybrid of R0 flags + R1 private tiles):
//   DATA: h published as u32 = (bf16 h << 16) | tag into a private,
//     contiguous 1KB tile per (parity, dir, bg, c); 2 coalesced atomic u64
//     stores per lane (hid-pairs packed via shfl_xor). No cross-block line
//     sharing on the store side.
//   FLAG: each producer drains its 2 stores (s_waitcnt vmcnt(0), ~16B) and
//     stores ONE flag = t+1 into its OWN 256B-aligned slot. Flags for a
//     chain group are spread 256B apart -> NO shared-line RMW serialization
//     at the coherent point (the R0 layout packed all 32 flags into one
//     128B line -> ~32 serialized line ops per step = the step-time floor).
//   CONSUMER: 32-lane spread-flag poll (monotone value >= t check against
//     parity-double-buffered slots), then inline coalesced h loads in the
//     MFMA loop (no register prefetch buffer, no retry-refetch).
//
// Overwrite safety (parity invariant): flag slot p gets value t+2 only after
// its producer observed ALL flags >= t+1, which requires every block to have
// finished step t, which requires every consumer to have passed its poll of
// slot p at value t. Same induction covers the data tiles.
// ---------------------------------------------------------------------------
__global__ __launch_bounds__(64, 1) void bilstm_persistent(
    const u16* __restrict__ wpack, const u16* __restrict__ xb,
    u32* __restrict__ hbuf, int* __restrict__ flags,
    const float* __restrict__ bf_, const float* __restrict__ bb_,
    float* __restrict__ out, u16* __restrict__ stage)
{
    const int l  = threadIdx.x;
    const int lm = l & 15;
    const int lq = l >> 4;
    const int chain = blockIdx.x & 7;
    const int c     = blockIdx.x >> 3;
    const int dir   = chain >> 2;
    const int bg    = chain & 3;

    __shared__ u16 wlds[4 * 16 * 512];   // 65536 B: h-part W, [(g*16+kh)*512 + lane*8 + j]

    // ---- stage h-part W into LDS (once) ----
#pragma unroll
    for (int g = 0; g < 4; ++g)
        for (int kh = 0; kh < 16; ++kh) {
            const u16* src = wpack + ((size_t)(dir * 128 + c * 4 + g) * 24 + 8 + kh) * 512 + l * 8;
            *(short8*)&wlds[(g * 16 + kh) * 512 + l * 8] = *(const short8*)src;
        }
    __syncthreads();

    const int hid = c * 16 + lm;
    const float* bias = dir ? bb_ : bf_;
    const float Bf = bias[hid];
    const float Bi = bias[HSZ + hid];
    const float Bo = bias[2 * HSZ + hid];
    const float Bg = bias[3 * HSZ + hid];
    float cst[4] = {0.f, 0.f, 0.f, 0.f};

    const u16* abx = xb + ((size_t)(bg * 16 + lm)) * ISZ + lq * 8;   // + tx*B_*ISZ
    const u16* wx  = wpack + ((size_t)(dir * 128 + c * 4) * 24) * 512 + l * 8;  // +(g*24+kb)*512

    // consumer: u64 base of the (parity,dir,bg) 32-tile span (tile = 128 u64)
    const u64* hb0 = (const u64*)hbuf + ((size_t)(0 * 2 + dir) * 4 + bg) * 32 * 128;
    const u64* hb1 = (const u64*)hbuf + ((size_t)(1 * 2 + dir) * 4 + bg) * 32 * 128;
    // lane-static u64 offset: tile (lq>>1 of each kb-pair), row lm, half (lq&1)
    const int lane_off = lm * 8 + (lq & 1) * 4 + (lq >> 1) * 128;

    // producer: u32 base of own tile, per parity
    u32* wt0 = hbuf + (((size_t)(0 * 2 + dir) * 4 + bg) * 32 + c) * 256;
    u32* wt1 = hbuf + (((size_t)(1 * 2 + dir) * 4 + bg) * 32 + c) * 256;
    const bool evenlane = (lm & 1) == 0;
    const int offA = evenlane ? (lq * 4 + 0) * 16 + lm : (lq * 4 + 1) * 16 + (lm - 1);
    const int offB = evenlane ? (lq * 4 + 2) * 16 + lm : (lq * 4 + 3) * 16 + (lm - 1);

    // flags: slot stride 64 ints (256 B). consumer polls parity t&1;
    // producer writes parity (t+1)&1 with value t+1.
    int* fl0 = flags + ((size_t)(0 * 8 + chain) * 32) * 64;   // parity 0 span
    int* fl1 = flags + ((size_t)(1 * 8 + chain) * 32) * 64;   // parity 1 span

    for (int t = 0; t < S_; ++t) {
        const int tx = dir ? (S_ - 1 - t) : t;

        floatx4 acc0 = (floatx4){0.f, 0.f, 0.f, 0.f};
        floatx4 acc1 = (floatx4){0.f, 0.f, 0.f, 0.f};
        floatx4 acc2 = (floatx4){0.f, 0.f, 0.f, 0.f};
        floatx4 acc3 = (floatx4){0.f, 0.f, 0.f, 0.f};

        // ---- x-part (recurrence-independent; W streams from L2, latency hidden)
        const u16* ax = abx + (size_t)tx * (B_ * ISZ);
#pragma unroll
        for (int kb = 0; kb < 8; ++kb) {
            short8 a  = *(const short8*)(ax + kb * 32);
            short8 w0 = *(const short8*)(wx + (size_t)(0 * 24 + kb) * 512);
            short8 w1 = *(const short8*)(wx + (size_t)(1 * 24 + kb) * 512);
            short8 w2 = *(const short8*)(wx + (size_t)(2 * 24 + kb) * 512);
            short8 w3 = *(const short8*)(wx + (size_t)(3 * 24 + kb) * 512);
            acc0 = __builtin_amdgcn_mfma_f32_16x16x32_bf16(a, w0, acc0, 0, 0, 0);
            acc1 = __builtin_amdgcn_mfma_f32_16x16x32_bf16(a, w1, acc1, 0, 0, 0);
            acc2 = __builtin_amdgcn_mfma_f32_16x16x32_bf16(a, w2, acc2, 0, 0, 0);
            acc3 = __builtin_amdgcn_mfma_f32_16x16x32_bf16(a, w3, acc3, 0, 0, 0);
        }

        // ---- wait for h(t): spread-flag poll, then inline h loads ----
        if (t > 0) {
            const int* fl = (t & 1) ? fl1 : fl0;
            for (;;) {
                int v = __hip_atomic_load(&fl[(l & 31) * 64], __ATOMIC_RELAXED,
                                          __HIP_MEMORY_SCOPE_AGENT);
                if (__ballot(v >= t) == ~0ull) break;
                __builtin_amdgcn_s_sleep(1);
            }
            asm volatile("" ::: "memory");   // no hoisting of h loads above poll

            const u64* hb = (t & 1) ? hb1 : hb0;   // parity t&1 holds h(t)
#pragma unroll
            for (int kb = 0; kb < 16; ++kb) {
                const u64* hp = hb + kb * 256 + lane_off;
                u64 q0 = __hip_atomic_load(hp + 0, __ATOMIC_RELAXED, __HIP_MEMORY_SCOPE_AGENT);
                u64 q1 = __hip_atomic_load(hp + 1, __ATOMIC_RELAXED, __HIP_MEMORY_SCOPE_AGENT);
                u64 q2 = __hip_atomic_load(hp + 2, __ATOMIC_RELAXED, __HIP_MEMORY_SCOPE_AGENT);
                u64 q3 = __hip_atomic_load(hp + 3, __ATOMIC_RELAXED, __HIP_MEMORY_SCOPE_AGENT);
                union { u32 u[4]; short8 s8; } ua;
                ua.u[0] = __builtin_amdgcn_perm((u32)(q0 >> 32), (u32)q0, 0x07060302u);
                ua.u[1] = __builtin_amdgcn_perm((u32)(q1 >> 32), (u32)q1, 0x07060302u);
                ua.u[2] = __builtin_amdgcn_perm((u32)(q2 >> 32), (u32)q2, 0x07060302u);
                ua.u[3] = __builtin_amdgcn_perm((u32)(q3 >> 32), (u32)q3, 0x07060302u);
                short8 a  = ua.s8;
                short8 w0 = *(const short8*)&wlds[(0 * 16 + kb) * 512 + l * 8];
                short8 w1 = *(const short8*)&wlds[(1 * 16 + kb) * 512 + l * 8];
                short8 w2 = *(const short8*)&wlds[(2 * 16 + kb) * 512 + l * 8];
                short8 w3 = *(const short8*)&wlds[(3 * 16 + kb) * 512 + l * 8];
                acc0 = __builtin_amdgcn_mfma_f32_16x16x32_bf16(a, w0, acc0, 0, 0, 0);
                acc1 = __builtin_amdgcn_mfma_f32_16x16x32_bf16(a, w1, acc1, 0, 0, 0);
                acc2 = __builtin_amdgcn_mfma_f32_16x16x32_bf16(a, w2, acc2, 0, 0, 0);
                acc3 = __builtin_amdgcn_mfma_f32_16x16x32_bf16(a, w3, acc3, 0, 0, 0);
            }
        }

        // ---- cell update: lane l owns batches bg*16+lq*4+r, hid = c*16+lm ----
        float hv[4];
        u32 pk[4];
#pragma unroll
        for (int r = 0; r < 4; ++r) {
            float fg = acc0[r] + Bf;
            float ig = acc1[r] + Bi;
            float og = acc2[r] + Bo;
            float gg = acc3[r] + Bg;
            float cn = sigmoidf_(fg) * cst[r] + sigmoidf_(ig) * tanhf_(gg);
            float hn = sigmoidf_(og) * tanhf_(cn);
            cst[r] = cn;
            hv[r] = hn;
            pk[r] = ((u32)f2bf(hn) << 16) | (u32)(t + 1);
        }

        // ---- publish: 2 coalesced atomic u64 stores, drain own 16B, 1 flag ----
        {
            u32* wt = ((t + 1) & 1) ? wt1 : wt0;
            u32 sx0 = __shfl_xor(pk[0], 1);
            u32 sx1 = __shfl_xor(pk[1], 1);
            u32 sx2 = __shfl_xor(pk[2], 1);
            u32 sx3 = __shfl_xor(pk[3], 1);
            u64 vA = evenlane ? (((u64)sx0 << 32) | pk[0]) : (((u64)pk[1] << 32) | sx1);
            u64 vB = evenlane ? (((u64)sx2 << 32) | pk[2]) : (((u64)pk[3] << 32) | sx3);
            __hip_atomic_store((u64*)(wt + offA), vA, __ATOMIC_RELAXED, __HIP_MEMORY_SCOPE_AGENT);
            __hip_atomic_store((u64*)(wt + offB), vB, __ATOMIC_RELAXED, __HIP_MEMORY_SCOPE_AGENT);
        }
        asm volatile("s_waitcnt vmcnt(0)" ::: "memory");
        {
            int* flw = ((t + 1) & 1) ? fl1 : fl0;
            if (l == 0)
                __hip_atomic_store(&flw[c * 64], t + 1, __ATOMIC_RELAXED,
                                   __HIP_MEMORY_SCOPE_AGENT);
        }

        // ---- deferred output (off critical path; plain stores) ----
#pragma unroll
        for (int r = 0; r < 4; ++r) {
            const int b = bg * 16 + lq * 4 + r;
            const size_t oidx = ((size_t)b * S_ + tx) * HSZ + hid;
            if (dir == 0) out[oidx] = 0.5f * hv[r];
            else          stage[oidx] = f2bf(hv[r]);
        }
    }
}

// out[i] += 0.5 * bf16(stage[i]); 4 elems/thread
__global__ __launch_bounds__(256) void combine(float* __restrict__ out,
                                               const u16* __restrict__ stage) {
    int i = (blockIdx.x * 256 + threadIdx.x) * 4;   // over 16,777,216
    ushort4 s = *(const ushort4*)(stage + i);
    float4 o = *(float4*)(out + i);
    o.x += 0.5f * __uint_as_float((uint32_t)s.x << 16);
    o.y += 0.5f * __uint_as_float((uint32_t)s.y << 16);
    o.z += 0.5f * __uint_as_float((uint32_t)s.z << 16);
    o.w += 0.5f * __uint_as_float((uint32_t)s.w << 16);
    *(float4*)(out + i) = o;
}

extern "C" void kernel_launch(void* const* d_in, const int* in_sizes, int n_in,
                              void* d_out, int out_size, void* d_ws, size_t ws_size,
                              hipStream_t stream) {
    const float* x  = (const float*)d_in[0];
    const float* Wf = (const float*)d_in[1];
    const float* bf = (const float*)d_in[2];
    const float* Wb = (const float*)d_in[3];
    const float* bb = (const float*)d_in[4];
    float* out = (float*)d_out;
    char* ws = (char*)d_ws;

    u16* wpack = (u16*)(ws + OFF_WPACK);
    u16* xb    = (u16*)(ws + OFF_XB);
    u32* hbuf  = (u32*)(ws + OFF_HB);
    int* flags = (int*)(ws + OFF_FLAGS);
    u16* stage = (u16*)(ws + OFF_STAGE);

    // zero tagged h tiles + flags (contiguous)
    (void)hipMemsetAsync(ws + OFF_HB, 0, 524288 + 131072, stream);

    pack_w<<<dim3(6144, 2), 256, 0, stream>>>(Wf, Wb, wpack);
    pack_x<<<dim3(32768), 256, 0, stream>>>(x, xb);

    bilstm_persistent<<<dim3(256), dim3(64), 0, stream>>>(
        wpack, xb, hbuf, flags, bf, bb, out, stage);

    combine<<<dim3(16384), 256, 0, stream>>>(out, stage);
}

// Round 4
// 3762.820 us; speedup vs baseline: 1.1587x; 1.1587x over previous
//
#include <hip/hip_runtime.h>
#include <cstdint>
#include <cstddef>

// Problem constants
#define B_   64
#define S_   512
#define ISZ  256
#define HSZ  512
#define NG   2048    // 4*H

typedef unsigned short u16;
typedef unsigned int   u32;
typedef unsigned long long u64;
typedef __attribute__((ext_vector_type(8))) short short8;
typedef __attribute__((ext_vector_type(4))) float floatx4;

// Workspace layout (bytes), total ~57.1 MB
static const size_t OFF_WPACK = 0;                        // 2*2048*768*2 = 6,291,456
static const size_t OFF_XB    = 6291456;                  // 512*64*256*2 = 16,777,216
static const size_t OFF_HB    = OFF_XB + 16777216;        // tagged h tiles: 2 parity * 2 dir * 4 bg * 32 c * 256 u32 * 4B = 524,288
static const size_t OFF_STAGE = OFF_HB + 524288;          // 512*64*512*2B = 33,554,432 (bwd h, bf16)

__device__ __forceinline__ u16 f2bf(float f) {
    uint32_t u = __float_as_uint(f);
    return (u16)((u + 0x7fffu + ((u >> 16) & 1u)) >> 16);  // RNE
}
__device__ __forceinline__ float sigmoidf_(float x) {
    return 1.0f / (1.0f + __expf(-x));
}
__device__ __forceinline__ float tanhf_(float x) {
    return 1.0f - 2.0f / (__expf(2.0f * x) + 1.0f);
}

// ---------------------------------------------------------------------------
// Pack W_f / W_b (768 x 2048 f32, row-major) into bf16 MFMA-B-fragment order,
// gate-interleaved per 16-hidden-unit chunk:
//   flat = ((dir*128 + nb)*24 + kb)*512 + lane*8 + j ;  nb = 4c+gate
// ---------------------------------------------------------------------------
__global__ __launch_bounds__(256) void pack_w(const float* __restrict__ Wf,
                                              const float* __restrict__ Wb,
                                              u16* __restrict__ wpack) {
    int tid = blockIdx.x * 256 + threadIdx.x;   // over 768*2048
    int dir = blockIdx.y;
    int p = tid & 2047;
    int k = tid >> 11;
    int gate = (p >> 4) & 3;
    int hid  = (p >> 6) * 16 + (p & 15);
    int col  = gate * HSZ + hid;
    const float* W = dir ? Wb : Wf;
    float v = W[(size_t)k * NG + col];
    int nb   = p >> 4;
    int lane = ((k & 31) >> 3) * 16 + (p & 15);
    size_t idx = (((size_t)(dir * 128 + nb) * 24 + (k >> 5)) * 512) + lane * 8 + (k & 7);
    wpack[idx] = f2bf(v);
}

// inputs (B,S,I) f32 -> Xb [t][b][i] bf16
__global__ __launch_bounds__(256) void pack_x(const float* __restrict__ x,
                                              u16* __restrict__ xb) {
    int tid = blockIdx.x * 256 + threadIdx.x;   // over S*B*I = 8,388,608
    int i = tid & 255;
    int b = (tid >> 8) & 63;
    int t = tid >> 14;
    xb[tid] = f2bf(x[((size_t)b * S_ + t) * ISZ + i]);
}

// ---------------------------------------------------------------------------
// Persistent BiLSTM. grid = 256 blocks x 64 threads (one wave per block).
//   chain = blockIdx&7 (dir = chain>>2, bg = chain&3), c = blockIdx>>3.
//
// ONE-HOP tagged-data handshake:
//   h published as u32 = (bf16 h << 16) | (t+1) into a private contiguous
//   1KB tile per (parity, dir, bg, c); 2 coalesced atomic u64 stores/lane.
//   NO drain, NO flag: data arrival IS the sync. Consumer PREFETCHES all
//   64 u64 at the end of the PREVIOUS step (latency overlaps its own
//   x-part), then per-kb validates 4 tags and selectively re-loads only
//   that kb's 4 u64 when stale (with s_sleep backoff so stale spins don't
//   flood the MALL and starve producer stores). Happy path adds ZERO
//   extra round trips.
//
// Software pipeline per iteration t:
//   [h-part: validate+MFMA (t>0)] -> cell -> publish h(t+1)
//   -> prefetch hq for t+1 -> x-part(t+1) from LDS W_x -> deferred stores(t)
//
// Overwrite safety (parity induction): tag t+2 is published only after the
// producer passed validate(t+1), which requires all blocks published t+1,
// which requires all blocks passed validate(t). Hence a validate expecting
// tag T can only ever observe tags T-2 (stale) or T (fresh) -- never a
// future tag -- and each u64 is individually atomic (no tearing).
// ---------------------------------------------------------------------------
__global__ __launch_bounds__(64, 1) void bilstm_persistent(
    const u16* __restrict__ wpack, const u16* __restrict__ xb,
    u32* __restrict__ hbuf,
    const float* __restrict__ bf_, const float* __restrict__ bb_,
    float* __restrict__ out, u16* __restrict__ stage)
{
    const int l  = threadIdx.x;
    const int lm = l & 15;
    const int lq = l >> 4;
    const int chain = blockIdx.x & 7;
    const int c     = blockIdx.x >> 3;
    const int dir   = chain >> 2;
    const int bg    = chain & 3;

    __shared__ u16 wlds[4 * 16 * 512];   // 65536 B: h-part W, [(g*16+kh)*512 + lane*8 + j]
    __shared__ u16 wxlds[4 * 8 * 512];   // 32768 B: x-part W, [(g*8+kb)*512 + lane*8 + j]

    // ---- stage W into LDS (once) ----
#pragma unroll
    for (int g = 0; g < 4; ++g) {
        for (int kh = 0; kh < 16; ++kh) {
            const u16* src = wpack + ((size_t)(dir * 128 + c * 4 + g) * 24 + 8 + kh) * 512 + l * 8;
            *(short8*)&wlds[(g * 16 + kh) * 512 + l * 8] = *(const short8*)src;
        }
        for (int kb = 0; kb < 8; ++kb) {
            const u16* src = wpack + ((size_t)(dir * 128 + c * 4 + g) * 24 + kb) * 512 + l * 8;
            *(short8*)&wxlds[(g * 8 + kb) * 512 + l * 8] = *(const short8*)src;
        }
    }
    __syncthreads();

    const int hid = c * 16 + lm;
    const float* bias = dir ? bb_ : bf_;
    const float Bf = bias[hid];
    const float Bi = bias[HSZ + hid];
    const float Bo = bias[2 * HSZ + hid];
    const float Bg = bias[3 * HSZ + hid];
    float cst[4] = {0.f, 0.f, 0.f, 0.f};

    const u16* abx = xb + ((size_t)(bg * 16 + lm)) * ISZ + lq * 8;   // + tx*B_*ISZ

    // consumer: u64 base of the (parity,dir,bg) 32-tile span (tile = 128 u64)
    const u64* hb0 = (const u64*)hbuf + ((size_t)(0 * 2 + dir) * 4 + bg) * 32 * 128;
    const u64* hb1 = (const u64*)hbuf + ((size_t)(1 * 2 + dir) * 4 + bg) * 32 * 128;
    // lane-static u64 offset: tile (lq>>1 of each kb-pair), row lm, half (lq&1)
    const int lane_off = lm * 8 + (lq & 1) * 4 + (lq >> 1) * 128;

    // producer: u32 base of own tile, per parity
    u32* wt0 = hbuf + (((size_t)(0 * 2 + dir) * 4 + bg) * 32 + c) * 256;
    u32* wt1 = hbuf + (((size_t)(1 * 2 + dir) * 4 + bg) * 32 + c) * 256;
    const bool evenlane = (lm & 1) == 0;
    const int offA = evenlane ? (lq * 4 + 0) * 16 + lm : (lq * 4 + 1) * 16 + (lm - 1);
    const int offB = evenlane ? (lq * 4 + 2) * 16 + lm : (lq * 4 + 3) * 16 + (lm - 1);

    floatx4 acc0, acc1, acc2, acc3;
    u64 hq[16][4];

    // ---- prologue: x-part for t = 0 ----
    {
        const int tx0 = dir ? (S_ - 1) : 0;
        acc0 = (floatx4){0.f, 0.f, 0.f, 0.f};
        acc1 = (floatx4){0.f, 0.f, 0.f, 0.f};
        acc2 = (floatx4){0.f, 0.f, 0.f, 0.f};
        acc3 = (floatx4){0.f, 0.f, 0.f, 0.f};
        const u16* ax = abx + (size_t)tx0 * (B_ * ISZ);
#pragma unroll
        for (int kb = 0; kb < 8; ++kb) {
            short8 a  = *(const short8*)(ax + kb * 32);
            short8 w0 = *(const short8*)&wxlds[(0 * 8 + kb) * 512 + l * 8];
            short8 w1 = *(const short8*)&wxlds[(1 * 8 + kb) * 512 + l * 8];
            short8 w2 = *(const short8*)&wxlds[(2 * 8 + kb) * 512 + l * 8];
            short8 w3 = *(const short8*)&wxlds[(3 * 8 + kb) * 512 + l * 8];
            acc0 = __builtin_amdgcn_mfma_f32_16x16x32_bf16(a, w0, acc0, 0, 0, 0);
            acc1 = __builtin_amdgcn_mfma_f32_16x16x32_bf16(a, w1, acc1, 0, 0, 0);
            acc2 = __builtin_amdgcn_mfma_f32_16x16x32_bf16(a, w2, acc2, 0, 0, 0);
            acc3 = __builtin_amdgcn_mfma_f32_16x16x32_bf16(a, w3, acc3, 0, 0, 0);
        }
    }

    for (int t = 0; t < S_; ++t) {
        const int tx = dir ? (S_ - 1 - t) : t;

        // ---- h-part: per-kb tag validate (selective reload + backoff) ----
        if (t > 0) {
            const u32 texp = (u32)t;
            const u64* hb = (t & 1) ? hb1 : hb0;
#pragma unroll
            for (int kb = 0; kb < 16; ++kb) {
                const u64* hp = hb + kb * 256 + lane_off;
                for (;;) {
                    int ok = (((u32)hq[kb][0] & 0xffffu) == texp) &
                             (((u32)hq[kb][1] & 0xffffu) == texp) &
                             (((u32)hq[kb][2] & 0xffffu) == texp) &
                             (((u32)hq[kb][3] & 0xffffu) == texp);
                    if (__ballot(ok != 0) == ~0ull) break;
                    __builtin_amdgcn_s_sleep(1);   // backoff: don't flood MALL
                    hq[kb][0] = __hip_atomic_load(hp + 0, __ATOMIC_RELAXED, __HIP_MEMORY_SCOPE_AGENT);
                    hq[kb][1] = __hip_atomic_load(hp + 1, __ATOMIC_RELAXED, __HIP_MEMORY_SCOPE_AGENT);
                    hq[kb][2] = __hip_atomic_load(hp + 2, __ATOMIC_RELAXED, __HIP_MEMORY_SCOPE_AGENT);
                    hq[kb][3] = __hip_atomic_load(hp + 3, __ATOMIC_RELAXED, __HIP_MEMORY_SCOPE_AGENT);
                }
                union { u32 u[4]; short8 s8; } ua;
                ua.u[0] = __builtin_amdgcn_perm((u32)(hq[kb][0] >> 32), (u32)hq[kb][0], 0x07060302u);
                ua.u[1] = __builtin_amdgcn_perm((u32)(hq[kb][1] >> 32), (u32)hq[kb][1], 0x07060302u);
                ua.u[2] = __builtin_amdgcn_perm((u32)(hq[kb][2] >> 32), (u32)hq[kb][2], 0x07060302u);
                ua.u[3] = __builtin_amdgcn_perm((u32)(hq[kb][3] >> 32), (u32)hq[kb][3], 0x07060302u);
                short8 a  = ua.s8;
                short8 w0 = *(const short8*)&wlds[(0 * 16 + kb) * 512 + l * 8];
                short8 w1 = *(const short8*)&wlds[(1 * 16 + kb) * 512 + l * 8];
                short8 w2 = *(const short8*)&wlds[(2 * 16 + kb) * 512 + l * 8];
                short8 w3 = *(const short8*)&wlds[(3 * 16 + kb) * 512 + l * 8];
                acc0 = __builtin_amdgcn_mfma_f32_16x16x32_bf16(a, w0, acc0, 0, 0, 0);
                acc1 = __builtin_amdgcn_mfma_f32_16x16x32_bf16(a, w1, acc1, 0, 0, 0);
                acc2 = __builtin_amdgcn_mfma_f32_16x16x32_bf16(a, w2, acc2, 0, 0, 0);
                acc3 = __builtin_amdgcn_mfma_f32_16x16x32_bf16(a, w3, acc3, 0, 0, 0);
            }
        }

        // ---- cell update: lane l owns batches bg*16+lq*4+r, hid = c*16+lm ----
        float hv[4];
        u32 pk[4];
#pragma unroll
        for (int r = 0; r < 4; ++r) {
            float fg = acc0[r] + Bf;
            float ig = acc1[r] + Bi;
            float og = acc2[r] + Bo;
            float gg = acc3[r] + Bg;
            float cn = sigmoidf_(fg) * cst[r] + sigmoidf_(ig) * tanhf_(gg);
            float hn = sigmoidf_(og) * tanhf_(cn);
            cst[r] = cn;
            hv[r] = hn;
            pk[r] = ((u32)f2bf(hn) << 16) | (u32)(t + 1);
        }

        // ---- publish: 2 coalesced atomic u64 stores; no drain, no flag ----
        {
            u32* wt = ((t + 1) & 1) ? wt1 : wt0;
            u32 sx0 = __shfl_xor(pk[0], 1);
            u32 sx1 = __shfl_xor(pk[1], 1);
            u32 sx2 = __shfl_xor(pk[2], 1);
            u32 sx3 = __shfl_xor(pk[3], 1);
            u64 vA = evenlane ? (((u64)sx0 << 32) | pk[0]) : (((u64)pk[1] << 32) | sx1);
            u64 vB = evenlane ? (((u64)sx2 << 32) | pk[2]) : (((u64)pk[3] << 32) | sx3);
            __hip_atomic_store((u64*)(wt + offA), vA, __ATOMIC_RELAXED, __HIP_MEMORY_SCOPE_AGENT);
            __hip_atomic_store((u64*)(wt + offB), vB, __ATOMIC_RELAXED, __HIP_MEMORY_SCOPE_AGENT);
        }

        if (t + 1 < S_) {
            // ---- prefetch hq for step t+1 (latency hides under x-part) ----
            const u64* hbn = ((t + 1) & 1) ? hb1 : hb0;
#pragma unroll
            for (int kb = 0; kb < 16; ++kb) {
                const u64* hp = hbn + kb * 256 + lane_off;
                hq[kb][0] = __hip_atomic_load(hp + 0, __ATOMIC_RELAXED, __HIP_MEMORY_SCOPE_AGENT);
                hq[kb][1] = __hip_atomic_load(hp + 1, __ATOMIC_RELAXED, __HIP_MEMORY_SCOPE_AGENT);
                hq[kb][2] = __hip_atomic_load(hp + 2, __ATOMIC_RELAXED, __HIP_MEMORY_SCOPE_AGENT);
                hq[kb][3] = __hip_atomic_load(hp + 3, __ATOMIC_RELAXED, __HIP_MEMORY_SCOPE_AGENT);
            }

            // ---- x-part for step t+1 (off critical path) ----
            const int txn = dir ? (S_ - 2 - t) : (t + 1);
            acc0 = (floatx4){0.f, 0.f, 0.f, 0.f};
            acc1 = (floatx4){0.f, 0.f, 0.f, 0.f};
            acc2 = (floatx4){0.f, 0.f, 0.f, 0.f};
            acc3 = (floatx4){0.f, 0.f, 0.f, 0.f};
            const u16* ax = abx + (size_t)txn * (B_ * ISZ);
#pragma unroll
            for (int kb = 0; kb < 8; ++kb) {
                short8 a  = *(const short8*)(ax + kb * 32);
                short8 w0 = *(const short8*)&wxlds[(0 * 8 + kb) * 512 + l * 8];
                short8 w1 = *(const short8*)&wxlds[(1 * 8 + kb) * 512 + l * 8];
                short8 w2 = *(const short8*)&wxlds[(2 * 8 + kb) * 512 + l * 8];
                short8 w3 = *(const short8*)&wxlds[(3 * 8 + kb) * 512 + l * 8];
                acc0 = __builtin_amdgcn_mfma_f32_16x16x32_bf16(a, w0, acc0, 0, 0, 0);
                acc1 = __builtin_amdgcn_mfma_f32_16x16x32_bf16(a, w1, acc1, 0, 0, 0);
                acc2 = __builtin_amdgcn_mfma_f32_16x16x32_bf16(a, w2, acc2, 0, 0, 0);
                acc3 = __builtin_amdgcn_mfma_f32_16x16x32_bf16(a, w3, acc3, 0, 0, 0);
            }
        }

        // ---- deferred output LAST ----
#pragma unroll
        for (int r = 0; r < 4; ++r) {
            const int b = bg * 16 + lq * 4 + r;
            const size_t oidx = ((size_t)b * S_ + tx) * HSZ + hid;
            if (dir == 0) out[oidx] = 0.5f * hv[r];
            else          stage[oidx] = f2bf(hv[r]);
        }
    }
}

// out[i] += 0.5 * bf16(stage[i]); 4 elems/thread
__global__ __launch_bounds__(256) void combine(float* __restrict__ out,
                                               const u16* __restrict__ stage) {
    int i = (blockIdx.x * 256 + threadIdx.x) * 4;   // over 16,777,216
    ushort4 s = *(const ushort4*)(stage + i);
    float4 o = *(float4*)(out + i);
    o.x += 0.5f * __uint_as_float((uint32_t)s.x << 16);
    o.y += 0.5f * __uint_as_float((uint32_t)s.y << 16);
    o.z += 0.5f * __uint_as_float((uint32_t)s.z << 16);
    o.w += 0.5f * __uint_as_float((uint32_t)s.w << 16);
    *(float4*)(out + i) = o;
}

extern "C" void kernel_launch(void* const* d_in, const int* in_sizes, int n_in,
                              void* d_out, int out_size, void* d_ws, size_t ws_size,
                              hipStream_t stream) {
    const float* x  = (const float*)d_in[0];
    const float* Wf = (const float*)d_in[1];
    const float* bf = (const float*)d_in[2];
    const float* Wb = (const float*)d_in[3];
    const float* bb = (const float*)d_in[4];
    float* out = (float*)d_out;
    char* ws = (char*)d_ws;

    u16* wpack = (u16*)(ws + OFF_WPACK);
    u16* xb    = (u16*)(ws + OFF_XB);
    u32* hbuf  = (u32*)(ws + OFF_HB);
    u16* stage = (u16*)(ws + OFF_STAGE);

    // zero tagged h tiles (tag 0 != any expected tag t>=1)
    (void)hipMemsetAsync(ws + OFF_HB, 0, 524288, stream);

    pack_w<<<dim3(6144, 2), 256, 0, stream>>>(Wf, Wb, wpack);
    pack_x<<<dim3(32768), 256, 0, stream>>>(x, xb);

    bilstm_persistent<<<dim3(256), dim3(64), 0, stream>>>(
        wpack, xb, hbuf, bf, bb, out, stage);

    combine<<<dim3(16384), 256, 0, stream>>>(out, stage);
}

// Round 5
// 3100.998 us; speedup vs baseline: 1.4060x; 1.2134x over previous
//
#include <hip/hip_runtime.h>
#include <cstdint>
#include <cstddef>

// Problem constants
#define B_   64
#define S_   512
#define ISZ  256
#define HSZ  512
#define NG   2048    // 4*H

typedef unsigned short u16;
typedef unsigned int   u32;
typedef unsigned long long u64;
typedef __attribute__((ext_vector_type(8))) short short8;
typedef __attribute__((ext_vector_type(4))) float floatx4;

// Workspace layout (bytes), total ~57.1 MB
static const size_t OFF_WPACK = 0;                        // 2*2048*768*2 = 6,291,456
static const size_t OFF_XB    = 6291456;                  // 512*64*256*2 = 16,777,216
static const size_t OFF_HB    = OFF_XB + 16777216;        // tagged h tiles: 2 parity * 2 dir * 4 bg * 32 c * 256 u32 * 4B = 524,288
static const size_t OFF_STAGE = OFF_HB + 524288;          // 512*64*512*2B = 33,554,432 (bwd h, bf16)

__device__ __forceinline__ u16 f2bf(float f) {
    uint32_t u = __float_as_uint(f);
    return (u16)((u + 0x7fffu + ((u >> 16) & 1u)) >> 16);  // RNE
}
__device__ __forceinline__ float sigmoidf_(float x) {
    return 1.0f / (1.0f + __expf(-x));
}
__device__ __forceinline__ float tanhf_(float x) {
    return 1.0f - 2.0f / (__expf(2.0f * x) + 1.0f);
}

// ---------------------------------------------------------------------------
// Pack W_f / W_b (768 x 2048 f32, row-major) into bf16 MFMA-B-fragment order,
// gate-interleaved per 16-hidden-unit chunk:
//   flat = ((dir*128 + nb)*24 + kb)*512 + lane*8 + j ;  nb = 4c+gate
// ---------------------------------------------------------------------------
__global__ __launch_bounds__(256) void pack_w(const float* __restrict__ Wf,
                                              const float* __restrict__ Wb,
                                              u16* __restrict__ wpack) {
    int tid = blockIdx.x * 256 + threadIdx.x;   // over 768*2048
    int dir = blockIdx.y;
    int p = tid & 2047;
    int k = tid >> 11;
    int gate = (p >> 4) & 3;
    int hid  = (p >> 6) * 16 + (p & 15);
    int col  = gate * HSZ + hid;
    const float* W = dir ? Wb : Wf;
    float v = W[(size_t)k * NG + col];
    int nb   = p >> 4;
    int lane = ((k & 31) >> 3) * 16 + (p & 15);
    size_t idx = (((size_t)(dir * 128 + nb) * 24 + (k >> 5)) * 512) + lane * 8 + (k & 7);
    wpack[idx] = f2bf(v);
}

// inputs (B,S,I) f32 -> Xb [t][b][i] bf16
__global__ __launch_bounds__(256) void pack_x(const float* __restrict__ x,
                                              u16* __restrict__ xb) {
    int tid = blockIdx.x * 256 + threadIdx.x;   // over S*B*I = 8,388,608
    int i = tid & 255;
    int b = (tid >> 8) & 63;
    int t = tid >> 14;
    xb[tid] = f2bf(x[((size_t)b * S_ + t) * ISZ + i]);
}

// ---------------------------------------------------------------------------
// Persistent BiLSTM. grid = 256 blocks x 64 threads (one wave per block).
//   chain = blockIdx&7 (dir = chain>>2, bg = chain&3), c = blockIdx>>3.
//
// ONE-HOP tagged-data handshake with BATCHED retry rounds:
//   h published as u32 = (bf16 h << 16) | (t+1) into a private contiguous
//   1KB tile per (parity, dir, bg, c); 2 coalesced atomic u64 stores/lane.
//   NO drain, NO flag. Consumer prefetches all 64 u64 at the end of the
//   previous step. Validate (R5 change vs R4): ONE pass computes a
//   wave-uniform 16-bit stale mask (ballot per kb); each retry ROUND
//   re-issues loads for ALL stale kbs back-to-back, waits ONCE, rechecks.
//   A round costs ~1 MALL round trip total -- vs R4's per-kb serialized
//   retry loops (~#stale x RT, the measured ~6.4us/step floor).
//   Self-validating registers need no fences or compiler barriers.
//
// Per-iteration order:
//   validate(t)+consume -> cell -> publish(t+1) -> deferred outputs(t)
//   -> prefetch hq(t+1) -> x-part(t+1) from LDS
// Deferred stores sit BEFORE the prefetch so their vmcnt drain overlaps
// producer-skew wait instead of the first validate of step t+1.
//
// Overwrite safety (parity induction): tag t+2 is published only after the
// producer passed validate(t+1), which requires all blocks published t+1,
// which requires all blocks passed validate(t). A validate expecting tag T
// observes only T-2 (stale) or T (fresh); each u64 is individually atomic.
// ---------------------------------------------------------------------------
__global__ __launch_bounds__(64, 1) void bilstm_persistent(
    const u16* __restrict__ wpack, const u16* __restrict__ xb,
    u32* __restrict__ hbuf,
    const float* __restrict__ bf_, const float* __restrict__ bb_,
    float* __restrict__ out, u16* __restrict__ stage)
{
    const int l  = threadIdx.x;
    const int lm = l & 15;
    const int lq = l >> 4;
    const int chain = blockIdx.x & 7;
    const int c     = blockIdx.x >> 3;
    const int dir   = chain >> 2;
    const int bg    = chain & 3;

    __shared__ u16 wlds[4 * 16 * 512];   // 65536 B: h-part W, [(g*16+kh)*512 + lane*8 + j]
    __shared__ u16 wxlds[4 * 8 * 512];   // 32768 B: x-part W, [(g*8+kb)*512 + lane*8 + j]

    // ---- stage W into LDS (once) ----
#pragma unroll
    for (int g = 0; g < 4; ++g) {
        for (int kh = 0; kh < 16; ++kh) {
            const u16* src = wpack + ((size_t)(dir * 128 + c * 4 + g) * 24 + 8 + kh) * 512 + l * 8;
            *(short8*)&wlds[(g * 16 + kh) * 512 + l * 8] = *(const short8*)src;
        }
        for (int kb = 0; kb < 8; ++kb) {
            const u16* src = wpack + ((size_t)(dir * 128 + c * 4 + g) * 24 + kb) * 512 + l * 8;
            *(short8*)&wxlds[(g * 8 + kb) * 512 + l * 8] = *(const short8*)src;
        }
    }
    __syncthreads();

    const int hid = c * 16 + lm;
    const float* bias = dir ? bb_ : bf_;
    const float Bf = bias[hid];
    const float Bi = bias[HSZ + hid];
    const float Bo = bias[2 * HSZ + hid];
    const float Bg = bias[3 * HSZ + hid];
    float cst[4] = {0.f, 0.f, 0.f, 0.f};

    const u16* abx = xb + ((size_t)(bg * 16 + lm)) * ISZ + lq * 8;   // + tx*B_*ISZ

    // consumer: u64 base of the (parity,dir,bg) 32-tile span (tile = 128 u64)
    const u64* hb0 = (const u64*)hbuf + ((size_t)(0 * 2 + dir) * 4 + bg) * 32 * 128;
    const u64* hb1 = (const u64*)hbuf + ((size_t)(1 * 2 + dir) * 4 + bg) * 32 * 128;
    // lane-static u64 offset: tile (lq>>1 of each kb-pair), row lm, half (lq&1)
    const int lane_off = lm * 8 + (lq & 1) * 4 + (lq >> 1) * 128;

    // producer: u32 base of own tile, per parity
    u32* wt0 = hbuf + (((size_t)(0 * 2 + dir) * 4 + bg) * 32 + c) * 256;
    u32* wt1 = hbuf + (((size_t)(1 * 2 + dir) * 4 + bg) * 32 + c) * 256;
    const bool evenlane = (lm & 1) == 0;
    const int offA = evenlane ? (lq * 4 + 0) * 16 + lm : (lq * 4 + 1) * 16 + (lm - 1);
    const int offB = evenlane ? (lq * 4 + 2) * 16 + lm : (lq * 4 + 3) * 16 + (lm - 1);

    floatx4 acc0, acc1, acc2, acc3;
    u64 hq[16][4];

    // ---- prologue: x-part for t = 0 ----
    {
        const int tx0 = dir ? (S_ - 1) : 0;
        acc0 = (floatx4){0.f, 0.f, 0.f, 0.f};
        acc1 = (floatx4){0.f, 0.f, 0.f, 0.f};
        acc2 = (floatx4){0.f, 0.f, 0.f, 0.f};
        acc3 = (floatx4){0.f, 0.f, 0.f, 0.f};
        const u16* ax = abx + (size_t)tx0 * (B_ * ISZ);
#pragma unroll
        for (int kb = 0; kb < 8; ++kb) {
            short8 a  = *(const short8*)(ax + kb * 32);
            short8 w0 = *(const short8*)&wxlds[(0 * 8 + kb) * 512 + l * 8];
            short8 w1 = *(const short8*)&wxlds[(1 * 8 + kb) * 512 + l * 8];
            short8 w2 = *(const short8*)&wxlds[(2 * 8 + kb) * 512 + l * 8];
            short8 w3 = *(const short8*)&wxlds[(3 * 8 + kb) * 512 + l * 8];
            acc0 = __builtin_amdgcn_mfma_f32_16x16x32_bf16(a, w0, acc0, 0, 0, 0);
            acc1 = __builtin_amdgcn_mfma_f32_16x16x32_bf16(a, w1, acc1, 0, 0, 0);
            acc2 = __builtin_amdgcn_mfma_f32_16x16x32_bf16(a, w2, acc2, 0, 0, 0);
            acc3 = __builtin_amdgcn_mfma_f32_16x16x32_bf16(a, w3, acc3, 0, 0, 0);
        }
    }

    for (int t = 0; t < S_; ++t) {
        const int tx = dir ? (S_ - 1 - t) : t;

        // ---- h-part: batched tag validate, then clean MFMA consume ----
        if (t > 0) {
            const u32 texp = (u32)t;
            const u64* hb = (t & 1) ? hb1 : hb0;

            // pass 1: wave-uniform stale mask over prefetched hq
            u32 stale = 0;
#pragma unroll
            for (int kb = 0; kb < 16; ++kb) {
                int ok = (((u32)hq[kb][0] & 0xffffu) == texp) &
                         (((u32)hq[kb][1] & 0xffffu) == texp) &
                         (((u32)hq[kb][2] & 0xffffu) == texp) &
                         (((u32)hq[kb][3] & 0xffffu) == texp);
                if (__ballot(ok != 0) != ~0ull) stale |= (1u << kb);
            }
            // batched retry rounds: reissue ALL stale kbs, one wait, recheck
            while (stale) {
                __builtin_amdgcn_s_sleep(2);   // throttle (outlier guard)
#pragma unroll
                for (int kb = 0; kb < 16; ++kb) {
                    if (stale & (1u << kb)) {
                        const u64* hp = hb + kb * 256 + lane_off;
                        hq[kb][0] = __hip_atomic_load(hp + 0, __ATOMIC_RELAXED, __HIP_MEMORY_SCOPE_AGENT);
                        hq[kb][1] = __hip_atomic_load(hp + 1, __ATOMIC_RELAXED, __HIP_MEMORY_SCOPE_AGENT);
                        hq[kb][2] = __hip_atomic_load(hp + 2, __ATOMIC_RELAXED, __HIP_MEMORY_SCOPE_AGENT);
                        hq[kb][3] = __hip_atomic_load(hp + 3, __ATOMIC_RELAXED, __HIP_MEMORY_SCOPE_AGENT);
                    }
                }
                u32 ns = 0;
#pragma unroll
                for (int kb = 0; kb < 16; ++kb) {
                    if (stale & (1u << kb)) {
                        int ok = (((u32)hq[kb][0] & 0xffffu) == texp) &
                                 (((u32)hq[kb][1] & 0xffffu) == texp) &
                                 (((u32)hq[kb][2] & 0xffffu) == texp) &
                                 (((u32)hq[kb][3] & 0xffffu) == texp);
                        if (__ballot(ok != 0) != ~0ull) ns |= (1u << kb);
                    }
                }
                stale = ns;
            }

            // consume: pure-register unpack + 64 MFMAs, no waits
#pragma unroll
            for (int kb = 0; kb < 16; ++kb) {
                union { u32 u[4]; short8 s8; } ua;
                ua.u[0] = __builtin_amdgcn_perm((u32)(hq[kb][0] >> 32), (u32)hq[kb][0], 0x07060302u);
                ua.u[1] = __builtin_amdgcn_perm((u32)(hq[kb][1] >> 32), (u32)hq[kb][1], 0x07060302u);
                ua.u[2] = __builtin_amdgcn_perm((u32)(hq[kb][2] >> 32), (u32)hq[kb][2], 0x07060302u);
                ua.u[3] = __builtin_amdgcn_perm((u32)(hq[kb][3] >> 32), (u32)hq[kb][3], 0x07060302u);
                short8 a  = ua.s8;
                short8 w0 = *(const short8*)&wlds[(0 * 16 + kb) * 512 + l * 8];
                short8 w1 = *(const short8*)&wlds[(1 * 16 + kb) * 512 + l * 8];
                short8 w2 = *(const short8*)&wlds[(2 * 16 + kb) * 512 + l * 8];
                short8 w3 = *(const short8*)&wlds[(3 * 16 + kb) * 512 + l * 8];
                acc0 = __builtin_amdgcn_mfma_f32_16x16x32_bf16(a, w0, acc0, 0, 0, 0);
                acc1 = __builtin_amdgcn_mfma_f32_16x16x32_bf16(a, w1, acc1, 0, 0, 0);
                acc2 = __builtin_amdgcn_mfma_f32_16x16x32_bf16(a, w2, acc2, 0, 0, 0);
                acc3 = __builtin_amdgcn_mfma_f32_16x16x32_bf16(a, w3, acc3, 0, 0, 0);
            }
        }

        // ---- cell update: lane l owns batches bg*16+lq*4+r, hid = c*16+lm ----
        float hv[4];
        u32 pk[4];
#pragma unroll
        for (int r = 0; r < 4; ++r) {
            float fg = acc0[r] + Bf;
            float ig = acc1[r] + Bi;
            float og = acc2[r] + Bo;
            float gg = acc3[r] + Bg;
            float cn = sigmoidf_(fg) * cst[r] + sigmoidf_(ig) * tanhf_(gg);
            float hn = sigmoidf_(og) * tanhf_(cn);
            cst[r] = cn;
            hv[r] = hn;
            pk[r] = ((u32)f2bf(hn) << 16) | (u32)(t + 1);
        }

        // ---- publish: 2 coalesced atomic u64 stores; no drain, no flag ----
        {
            u32* wt = ((t + 1) & 1) ? wt1 : wt0;
            u32 sx0 = __shfl_xor(pk[0], 1);
            u32 sx1 = __shfl_xor(pk[1], 1);
            u32 sx2 = __shfl_xor(pk[2], 1);
            u32 sx3 = __shfl_xor(pk[3], 1);
            u64 vA = evenlane ? (((u64)sx0 << 32) | pk[0]) : (((u64)pk[1] << 32) | sx1);
            u64 vB = evenlane ? (((u64)sx2 << 32) | pk[2]) : (((u64)pk[3] << 32) | sx3);
            __hip_atomic_store((u64*)(wt + offA), vA, __ATOMIC_RELAXED, __HIP_MEMORY_SCOPE_AGENT);
            __hip_atomic_store((u64*)(wt + offB), vB, __ATOMIC_RELAXED, __HIP_MEMORY_SCOPE_AGENT);
        }

        // ---- deferred output (before prefetch: store-drain overlaps
        //      producer-skew wait rather than the next validate) ----
#pragma unroll
        for (int r = 0; r < 4; ++r) {
            const int b = bg * 16 + lq * 4 + r;
            const size_t oidx = ((size_t)b * S_ + tx) * HSZ + hid;
            if (dir == 0) out[oidx] = 0.5f * hv[r];
            else          stage[oidx] = f2bf(hv[r]);
        }

        if (t + 1 < S_) {
            // ---- prefetch hq for step t+1 (latency hides under x-part) ----
            const u64* hbn = ((t + 1) & 1) ? hb1 : hb0;
#pragma unroll
            for (int kb = 0; kb < 16; ++kb) {
                const u64* hp = hbn + kb * 256 + lane_off;
                hq[kb][0] = __hip_atomic_load(hp + 0, __ATOMIC_RELAXED, __HIP_MEMORY_SCOPE_AGENT);
                hq[kb][1] = __hip_atomic_load(hp + 1, __ATOMIC_RELAXED, __HIP_MEMORY_SCOPE_AGENT);
                hq[kb][2] = __hip_atomic_load(hp + 2, __ATOMIC_RELAXED, __HIP_MEMORY_SCOPE_AGENT);
                hq[kb][3] = __hip_atomic_load(hp + 3, __ATOMIC_RELAXED, __HIP_MEMORY_SCOPE_AGENT);
            }

            // ---- x-part for step t+1 (off critical path) ----
            const int txn = dir ? (S_ - 2 - t) : (t + 1);
            acc0 = (floatx4){0.f, 0.f, 0.f, 0.f};
            acc1 = (floatx4){0.f, 0.f, 0.f, 0.f};
            acc2 = (floatx4){0.f, 0.f, 0.f, 0.f};
            acc3 = (floatx4){0.f, 0.f, 0.f, 0.f};
            const u16* ax = abx + (size_t)txn * (B_ * ISZ);
#pragma unroll
            for (int kb = 0; kb < 8; ++kb) {
                short8 a  = *(const short8*)(ax + kb * 32);
                short8 w0 = *(const short8*)&wxlds[(0 * 8 + kb) * 512 + l * 8];
                short8 w1 = *(const short8*)&wxlds[(1 * 8 + kb) * 512 + l * 8];
                short8 w2 = *(const short8*)&wxlds[(2 * 8 + kb) * 512 + l * 8];
                short8 w3 = *(const short8*)&wxlds[(3 * 8 + kb) * 512 + l * 8];
                acc0 = __builtin_amdgcn_mfma_f32_16x16x32_bf16(a, w0, acc0, 0, 0, 0);
                acc1 = __builtin_amdgcn_mfma_f32_16x16x32_bf16(a, w1, acc1, 0, 0, 0);
                acc2 = __builtin_amdgcn_mfma_f32_16x16x32_bf16(a, w2, acc2, 0, 0, 0);
                acc3 = __builtin_amdgcn_mfma_f32_16x16x32_bf16(a, w3, acc3, 0, 0, 0);
            }
        }
    }
}

// out[i] += 0.5 * bf16(stage[i]); 4 elems/thread
__global__ __launch_bounds__(256) void combine(float* __restrict__ out,
                                               const u16* __restrict__ stage) {
    int i = (blockIdx.x * 256 + threadIdx.x) * 4;   // over 16,777,216
    ushort4 s = *(const ushort4*)(stage + i);
    float4 o = *(float4*)(out + i);
    o.x += 0.5f * __uint_as_float((uint32_t)s.x << 16);
    o.y += 0.5f * __uint_as_float((uint32_t)s.y << 16);
    o.z += 0.5f * __uint_as_float((uint32_t)s.z << 16);
    o.w += 0.5f * __uint_as_float((uint32_t)s.w << 16);
    *(float4*)(out + i) = o;
}

extern "C" void kernel_launch(void* const* d_in, const int* in_sizes, int n_in,
                              void* d_out, int out_size, void* d_ws, size_t ws_size,
                              hipStream_t stream) {
    const float* x  = (const float*)d_in[0];
    const float* Wf = (const float*)d_in[1];
    const float* bf = (const float*)d_in[2];
    const float* Wb = (const float*)d_in[3];
    const float* bb = (const float*)d_in[4];
    float* out = (float*)d_out;
    char* ws = (char*)d_ws;

    u16* wpack = (u16*)(ws + OFF_WPACK);
    u16* xb    = (u16*)(ws + OFF_XB);
    u32* hbuf  = (u32*)(ws + OFF_HB);
    u16* stage = (u16*)(ws + OFF_STAGE);

    // zero tagged h tiles (tag 0 != any expected tag t>=1)
    (void)hipMemsetAsync(ws + OFF_HB, 0, 524288, stream);

    pack_w<<<dim3(6144, 2), 256, 0, stream>>>(Wf, Wb, wpack);
    pack_x<<<dim3(32768), 256, 0, stream>>>(x, xb);

    bilstm_persistent<<<dim3(256), dim3(64), 0, stream>>>(
        wpack, xb, hbuf, bf, bb, out, stage);

    combine<<<dim3(16384), 256, 0, stream>>>(out, stage);
}

// Round 7
// 2359.791 us; speedup vs baseline: 1.8476x; 1.3141x over previous
//
#include <hip/hip_runtime.h>
#include <cstdint>
#include <cstddef>

// Problem constants
#define B_   64
#define S_   512
#define ISZ  256
#define HSZ  512
#define NG   2048    // 4*H

typedef unsigned short u16;
typedef unsigned int   u32;
typedef unsigned long long u64;
typedef __attribute__((ext_vector_type(8))) short short8;
typedef __attribute__((ext_vector_type(4))) float floatx4;
typedef __attribute__((ext_vector_type(4))) int   int4v;

// Workspace layout (bytes), total ~57.1 MB
static const size_t OFF_WPACK = 0;                        // 2*2048*768*2 = 6,291,456
static const size_t OFF_XB    = 6291456;                  // 512*64*256*2 = 16,777,216
static const size_t OFF_HB    = OFF_XB + 16777216;        // gather imgs: 2 par * 8 chain * 8192 u32 = 524,288
static const size_t OFF_STAGE = OFF_HB + 524288;          // 512*64*512*2B = 33,554,432 (bwd h, bf16)

__device__ __forceinline__ u16 f2bf(float f) {
    uint32_t u = __float_as_uint(f);
    return (u16)((u + 0x7fffu + ((u >> 16) & 1u)) >> 16);  // RNE
}
__device__ __forceinline__ float sigmoidf_(float x) {
    return 1.0f / (1.0f + __expf(-x));
}
__device__ __forceinline__ float tanhf_(float x) {
    return 1.0f - 2.0f / (__expf(2.0f * x) + 1.0f);
}

// ---------------------------------------------------------------------------
// Pack W_f / W_b (768 x 2048 f32, row-major) into bf16 MFMA-B-fragment order,
// gate-interleaved per 16-hidden-unit chunk:
//   flat = ((dir*128 + nb)*24 + kb)*512 + lane*8 + j ;  nb = 4c+gate
// ---------------------------------------------------------------------------
__global__ __launch_bounds__(256) void pack_w(const float* __restrict__ Wf,
                                              const float* __restrict__ Wb,
                                              u16* __restrict__ wpack) {
    int tid = blockIdx.x * 256 + threadIdx.x;   // over 768*2048
    int dir = blockIdx.y;
    int p = tid & 2047;
    int k = tid >> 11;
    int gate = (p >> 4) & 3;
    int hid  = (p >> 6) * 16 + (p & 15);
    int col  = gate * HSZ + hid;
    const float* W = dir ? Wb : Wf;
    float v = W[(size_t)k * NG + col];
    int nb   = p >> 4;
    int lane = ((k & 31) >> 3) * 16 + (p & 15);
    size_t idx = (((size_t)(dir * 128 + nb) * 24 + (k >> 5)) * 512) + lane * 8 + (k & 7);
    wpack[idx] = f2bf(v);
}

// inputs (B,S,I) f32 -> Xb [t][b][i] bf16
__global__ __launch_bounds__(256) void pack_x(const float* __restrict__ x,
                                              u16* __restrict__ xb) {
    int tid = blockIdx.x * 256 + threadIdx.x;   // over S*B*I = 8,388,608
    int i = tid & 255;
    int b = (tid >> 8) & 63;
    int t = tid >> 14;
    xb[tid] = f2bf(x[((size_t)b * S_ + t) * ISZ + i]);
}

// ---------------------------------------------------------------------------
// Persistent BiLSTM. grid = 256 blocks x 64 threads (one wave per block).
//   chain = blockIdx&7 (dir = chain>>2, bg = chain&3), c = blockIdx>>3.
//
// CONSUMER-MAJOR tagged gather image:
//   exchange buffer G32[kb][lane][j] (u32 = (bf16 h << 16) | tag): each
//   consumer load instruction reads a CONTIGUOUS 2KB (dwordx4 x2 per kb,
//   every 64B sector fully used) -- fixes R5's 4x sector over-fetch
//   (~2048 transactions/wave-step). Producers make 4 scattered u32 agent
//   stores (fire-and-forget, off critical path).
//   Consumer: lane l=(lq*16+lm), kb: h[bg*16+lm][kb*32+lq*8+j] at
//   idx = kb*512 + l*8 + j.  Producer (c, lane lm, batches lq*4+r):
//   idx = (c>>1)*512 + ((c&1)*2+(lm>>3))*128 + (lq*4+r)*8 + (lm&7).
//   (Bijection re-verified both directions.)
//
// PINNED asm prefetch: global_load_dwordx4 ... sc0 sc1 issued via volatile
// inline asm at the END of the previous iteration (cannot be sunk -- R5's
// VGPR=144 proved the intrinsic prefetch was sunk to its use). Validate
// opens with s_waitcnt vmcnt(0) + sched_barrier(0) (rule-18 pattern).
// ax loads issue BEFORE the prefetch asm (older in vmcnt queue).
//
// Batched retry rounds: wave-uniform stale mask; each round reissues all
// stale kbs, one wait, recheck; s_sleep throttle at round start.
//
// Overwrite safety (parity induction): tag t+2 is published only after the
// producer passed validate(t+1), which requires all blocks published t+1,
// which requires all blocks passed validate(t). A validate expecting tag T
// observes only T-2 (stale) or T (fresh); each u32 is individually atomic.
// Liveness: all 256 blocks co-resident (grid == CU count); publish precedes
// validate; relaxed agent stores eventually visible; sc0 sc1 loads bypass
// all caches -> no stale-forever, no circular wait.
// ---------------------------------------------------------------------------
__global__ __launch_bounds__(64, 1) void bilstm_persistent(
    const u16* __restrict__ wpack, const u16* __restrict__ xb,
    u32* __restrict__ hbuf,
    const float* __restrict__ bf_, const float* __restrict__ bb_,
    float* __restrict__ out, u16* __restrict__ stage)
{
    const int l  = threadIdx.x;
    const int lm = l & 15;
    const int lq = l >> 4;
    const int chain = blockIdx.x & 7;
    const int c     = blockIdx.x >> 3;
    const int dir   = chain >> 2;
    const int bg    = chain & 3;

    __shared__ u16 wlds[4 * 16 * 512];   // 65536 B: h-part W, [(g*16+kh)*512 + lane*8 + j]
    __shared__ u16 wxlds[4 * 8 * 512];   // 32768 B: x-part W, [(g*8+kb)*512 + lane*8 + j]

    // ---- stage W into LDS (once) ----
#pragma unroll
    for (int g = 0; g < 4; ++g) {
        for (int kh = 0; kh < 16; ++kh) {
            const u16* src = wpack + ((size_t)(dir * 128 + c * 4 + g) * 24 + 8 + kh) * 512 + l * 8;
            *(short8*)&wlds[(g * 16 + kh) * 512 + l * 8] = *(const short8*)src;
        }
        for (int kb = 0; kb < 8; ++kb) {
            const u16* src = wpack + ((size_t)(dir * 128 + c * 4 + g) * 24 + kb) * 512 + l * 8;
            *(short8*)&wxlds[(g * 8 + kb) * 512 + l * 8] = *(const short8*)src;
        }
    }
    __syncthreads();

    const int hid = c * 16 + lm;
    const float* bias = dir ? bb_ : bf_;
    const float Bf = bias[hid];
    const float Bi = bias[HSZ + hid];
    const float Bo = bias[2 * HSZ + hid];
    const float Bg = bias[3 * HSZ + hid];
    float cst[4] = {0.f, 0.f, 0.f, 0.f};

    const u16* abx = xb + ((size_t)(bg * 16 + lm)) * ISZ + lq * 8;   // + tx*B_*ISZ

    // gather images (8192 u32 per parity x chain)
    u32* G0 = hbuf + ((size_t)(0 * 2 + dir) * 4 + bg) * 8192;
    u32* G1 = hbuf + ((size_t)(1 * 2 + dir) * 4 + bg) * 8192;
    // consumer: per-lane byte pointer (kb adds kb*2048)
    const char* gq0 = (const char*)G0 + l * 32;
    const char* gq1 = (const char*)G1 + l * 32;
    // producer: u32 base index (r adds (lq*4+r)*8)
    const int pbase = (c >> 1) * 512 + ((c & 1) * 2 + (lm >> 3)) * 128 + (lm & 7);

    floatx4 acc0, acc1, acc2, acc3;
    int4v hv4[16][2];   // per kb: j0..3, j4..7 (u32 = bf16<<16 | tag)

    // ---- prologue: x-part for t = 0 ----
    {
        const int tx0 = dir ? (S_ - 1) : 0;
        acc0 = (floatx4){0.f, 0.f, 0.f, 0.f};
        acc1 = (floatx4){0.f, 0.f, 0.f, 0.f};
        acc2 = (floatx4){0.f, 0.f, 0.f, 0.f};
        acc3 = (floatx4){0.f, 0.f, 0.f, 0.f};
        const u16* ax = abx + (size_t)tx0 * (B_ * ISZ);
#pragma unroll
        for (int kb = 0; kb < 8; ++kb) {
            short8 a  = *(const short8*)(ax + kb * 32);
            short8 w0 = *(const short8*)&wxlds[(0 * 8 + kb) * 512 + l * 8];
            short8 w1 = *(const short8*)&wxlds[(1 * 8 + kb) * 512 + l * 8];
            short8 w2 = *(const short8*)&wxlds[(2 * 8 + kb) * 512 + l * 8];
            short8 w3 = *(const short8*)&wxlds[(3 * 8 + kb) * 512 + l * 8];
            acc0 = __builtin_amdgcn_mfma_f32_16x16x32_bf16(a, w0, acc0, 0, 0, 0);
            acc1 = __builtin_amdgcn_mfma_f32_16x16x32_bf16(a, w1, acc1, 0, 0, 0);
            acc2 = __builtin_amdgcn_mfma_f32_16x16x32_bf16(a, w2, acc2, 0, 0, 0);
            acc3 = __builtin_amdgcn_mfma_f32_16x16x32_bf16(a, w3, acc3, 0, 0, 0);
        }
    }

    for (int t = 0; t < S_; ++t) {
        const int tx = dir ? (S_ - 1 - t) : t;

        // ---- h-part: wait prefetch, tag validate (batched), consume ----
        if (t > 0) {
            asm volatile("s_waitcnt vmcnt(0)" ::: "memory");
            __builtin_amdgcn_sched_barrier(0);

            const u32 texp = (u32)t;
            const u32 e2 = texp | (texp << 16);
            const char* gq = (t & 1) ? gq1 : gq0;

            // pass 1: wave-uniform stale mask
            u32 stale = 0;
#pragma unroll
            for (int kb = 0; kb < 16; ++kb) {
                const int4v A = hv4[kb][0];
                const int4v B = hv4[kb][1];
                u32 p0 = __builtin_amdgcn_perm((u32)A.y, (u32)A.x, 0x05040100u);
                u32 p1 = __builtin_amdgcn_perm((u32)A.w, (u32)A.z, 0x05040100u);
                u32 p2 = __builtin_amdgcn_perm((u32)B.y, (u32)B.x, 0x05040100u);
                u32 p3 = __builtin_amdgcn_perm((u32)B.w, (u32)B.z, 0x05040100u);
                int ok = (p0 == e2) & (p1 == e2) & (p2 == e2) & (p3 == e2);
                if (__ballot(ok != 0) != ~0ull) stale |= (1u << kb);
            }
            // batched retry rounds
            while (stale) {
                __builtin_amdgcn_s_sleep(1);   // throttle each round
#pragma unroll
                for (int kb = 0; kb < 16; ++kb) {
                    if (stale & (1u << kb)) {
                        const void* hp = gq + kb * 2048;
                        asm volatile("global_load_dwordx4 %0, %2, off sc0 sc1\n\t"
                                     "global_load_dwordx4 %1, %2, off offset:16 sc0 sc1"
                                     : "=&v"(hv4[kb][0]), "=&v"(hv4[kb][1])
                                     : "v"(hp));
                    }
                }
                asm volatile("s_waitcnt vmcnt(0)" ::: "memory");
                __builtin_amdgcn_sched_barrier(0);
                u32 ns = 0;
#pragma unroll
                for (int kb = 0; kb < 16; ++kb) {
                    if (stale & (1u << kb)) {
                        const int4v A = hv4[kb][0];
                        const int4v B = hv4[kb][1];
                        u32 p0 = __builtin_amdgcn_perm((u32)A.y, (u32)A.x, 0x05040100u);
                        u32 p1 = __builtin_amdgcn_perm((u32)A.w, (u32)A.z, 0x05040100u);
                        u32 p2 = __builtin_amdgcn_perm((u32)B.y, (u32)B.x, 0x05040100u);
                        u32 p3 = __builtin_amdgcn_perm((u32)B.w, (u32)B.z, 0x05040100u);
                        int ok = (p0 == e2) & (p1 == e2) & (p2 == e2) & (p3 == e2);
                        if (__ballot(ok != 0) != ~0ull) ns |= (1u << kb);
                    }
                }
                stale = ns;
            }

            // consume: pure-register unpack + 64 MFMAs
#pragma unroll
            for (int kb = 0; kb < 16; ++kb) {
                const int4v A = hv4[kb][0];
                const int4v B = hv4[kb][1];
                union { u32 u[4]; short8 s8; } ua;
                ua.u[0] = __builtin_amdgcn_perm((u32)A.y, (u32)A.x, 0x07060302u);
                ua.u[1] = __builtin_amdgcn_perm((u32)A.w, (u32)A.z, 0x07060302u);
                ua.u[2] = __builtin_amdgcn_perm((u32)B.y, (u32)B.x, 0x07060302u);
                ua.u[3] = __builtin_amdgcn_perm((u32)B.w, (u32)B.z, 0x07060302u);
                short8 a  = ua.s8;
                short8 w0 = *(const short8*)&wlds[(0 * 16 + kb) * 512 + l * 8];
                short8 w1 = *(const short8*)&wlds[(1 * 16 + kb) * 512 + l * 8];
                short8 w2 = *(const short8*)&wlds[(2 * 16 + kb) * 512 + l * 8];
                short8 w3 = *(const short8*)&wlds[(3 * 16 + kb) * 512 + l * 8];
                acc0 = __builtin_amdgcn_mfma_f32_16x16x32_bf16(a, w0, acc0, 0, 0, 0);
                acc1 = __builtin_amdgcn_mfma_f32_16x16x32_bf16(a, w1, acc1, 0, 0, 0);
                acc2 = __builtin_amdgcn_mfma_f32_16x16x32_bf16(a, w2, acc2, 0, 0, 0);
                acc3 = __builtin_amdgcn_mfma_f32_16x16x32_bf16(a, w3, acc3, 0, 0, 0);
            }
        }

        // ---- cell update: lane l owns batches bg*16+lq*4+r, hid = c*16+lm ----
        float hv[4];
        u32 pk[4];
#pragma unroll
        for (int r = 0; r < 4; ++r) {
            float fg = acc0[r] + Bf;
            float ig = acc1[r] + Bi;
            float og = acc2[r] + Bo;
            float gg = acc3[r] + Bg;
            float cn = sigmoidf_(fg) * cst[r] + sigmoidf_(ig) * tanhf_(gg);
            float hn = sigmoidf_(og) * tanhf_(cn);
            cst[r] = cn;
            hv[r] = hn;
            pk[r] = ((u32)f2bf(hn) << 16) | (u32)(t + 1);
        }

        // ---- publish: 4 scattered u32 agent stores (off critical path) ----
        {
            u32* wt = ((t + 1) & 1) ? G1 : G0;
#pragma unroll
            for (int r = 0; r < 4; ++r)
                __hip_atomic_store(&wt[pbase + (lq * 4 + r) * 8], pk[r],
                                   __ATOMIC_RELAXED, __HIP_MEMORY_SCOPE_AGENT);
        }

        // ---- deferred output ----
#pragma unroll
        for (int r = 0; r < 4; ++r) {
            const int b = bg * 16 + lq * 4 + r;
            const size_t oidx = ((size_t)b * S_ + tx) * HSZ + hid;
            if (dir == 0) out[oidx] = 0.5f * hv[r];
            else          stage[oidx] = f2bf(hv[r]);
        }

        if (t + 1 < S_) {
            // ---- ax loads FIRST (older in vmcnt queue than the prefetch) ----
            const int txn = dir ? (S_ - 2 - t) : (t + 1);
            const u16* ax = abx + (size_t)txn * (B_ * ISZ);
            short8 axr[8];
#pragma unroll
            for (int kb = 0; kb < 8; ++kb)
                axr[kb] = *(const short8*)(ax + kb * 32);

            __builtin_amdgcn_sched_barrier(0);

            // ---- pinned prefetch for step t+1 (issue-only, coalesced 2KB/instr)
            {
                const char* gqn = ((t + 1) & 1) ? gq1 : gq0;
#pragma unroll
                for (int kb = 0; kb < 16; ++kb) {
                    const void* hp = gqn + kb * 2048;
                    asm volatile("global_load_dwordx4 %0, %2, off sc0 sc1\n\t"
                                 "global_load_dwordx4 %1, %2, off offset:16 sc0 sc1"
                                 : "=&v"(hv4[kb][0]), "=&v"(hv4[kb][1])
                                 : "v"(hp));
                }
            }

            // ---- x-part for step t+1 (overlaps prefetch flight) ----
            acc0 = (floatx4){0.f, 0.f, 0.f, 0.f};
            acc1 = (floatx4){0.f, 0.f, 0.f, 0.f};
            acc2 = (floatx4){0.f, 0.f, 0.f, 0.f};
            acc3 = (floatx4){0.f, 0.f, 0.f, 0.f};
#pragma unroll
            for (int kb = 0; kb < 8; ++kb) {
                short8 a  = axr[kb];
                short8 w0 = *(const short8*)&wxlds[(0 * 8 + kb) * 512 + l * 8];
                short8 w1 = *(const short8*)&wxlds[(1 * 8 + kb) * 512 + l * 8];
                short8 w2 = *(const short8*)&wxlds[(2 * 8 + kb) * 512 + l * 8];
                short8 w3 = *(const short8*)&wxlds[(3 * 8 + kb) * 512 + l * 8];
                acc0 = __builtin_amdgcn_mfma_f32_16x16x32_bf16(a, w0, acc0, 0, 0, 0);
                acc1 = __builtin_amdgcn_mfma_f32_16x16x32_bf16(a, w1, acc1, 0, 0, 0);
                acc2 = __builtin_amdgcn_mfma_f32_16x16x32_bf16(a, w2, acc2, 0, 0, 0);
                acc3 = __builtin_amdgcn_mfma_f32_16x16x32_bf16(a, w3, acc3, 0, 0, 0);
            }
        }
    }
}

// out[i] += 0.5 * bf16(stage[i]); 4 elems/thread
__global__ __launch_bounds__(256) void combine(float* __restrict__ out,
                                               const u16* __restrict__ stage) {
    int i = (blockIdx.x * 256 + threadIdx.x) * 4;   // over 16,777,216
    ushort4 s = *(const ushort4*)(stage + i);
    float4 o = *(float4*)(out + i);
    o.x += 0.5f * __uint_as_float((uint32_t)s.x << 16);
    o.y += 0.5f * __uint_as_float((uint32_t)s.y << 16);
    o.z += 0.5f * __uint_as_float((uint32_t)s.z << 16);
    o.w += 0.5f * __uint_as_float((uint32_t)s.w << 16);
    *(float4*)(out + i) = o;
}

extern "C" void kernel_launch(void* const* d_in, const int* in_sizes, int n_in,
                              void* d_out, int out_size, void* d_ws, size_t ws_size,
                              hipStream_t stream) {
    const float* x  = (const float*)d_in[0];
    const float* Wf = (const float*)d_in[1];
    const float* bf = (const float*)d_in[2];
    const float* Wb = (const float*)d_in[3];
    const float* bb = (const float*)d_in[4];
    float* out = (float*)d_out;
    char* ws = (char*)d_ws;

    u16* wpack = (u16*)(ws + OFF_WPACK);
    u16* xb    = (u16*)(ws + OFF_XB);
    u32* hbuf  = (u32*)(ws + OFF_HB);
    u16* stage = (u16*)(ws + OFF_STAGE);

    // zero gather images (tag 0 != any expected tag t>=1)
    (void)hipMemsetAsync(ws + OFF_HB, 0, 524288, stream);

    pack_w<<<dim3(6144, 2), 256, 0, stream>>>(Wf, Wb, wpack);
    pack_x<<<dim3(32768), 256, 0, stream>>>(x, xb);

    bilstm_persistent<<<dim3(256), dim3(64), 0, stream>>>(
        wpack, xb, hbuf, bf, bb, out, stage);

    combine<<<dim3(16384), 256, 0, stream>>>(out, stage);
}